// Round 12
// baseline (62.238 us; speedup 1.0000x reference)
//
#include <hip/hip_runtime.h>

#define NELEMS 10
#define W_SHIFT 10             // bucket width = 1024 nodes
#define W 1024
#define MAXBL 128              // max buckets supported by LDS arrays
#define CHUNK 4096             // edges per sort chunk
#define EPT 8                  // edges per thread (CHUNK / BS)
#define BS 512
#define PAD 4                  // segment padding (vector alignment only)
#define SLABCAP (CHUNK + MAXBL * (PAD - 1))   // 4480
#define PKCAP 50176            // 49KB packed elem capacity (<=100352 nodes)
#define GRIDP 512              // persistent blocks (2 per CU)
#define INV_A_PREF (1.0f / (0.4543f * 0.529f))

// ase covalent radii (Cordero 2008), padded to 119
__constant__ float c_cov[119] = {
    0.2f, 0.31f, 0.28f, 1.28f, 0.96f, 0.84f, 0.76f, 0.71f, 0.66f, 0.57f, 0.58f, 1.66f,
    1.41f, 1.21f, 1.11f, 1.07f, 1.05f, 1.02f, 1.06f, 2.03f, 1.76f, 1.70f, 1.60f, 1.53f,
    1.39f, 1.39f, 1.32f, 1.26f, 1.24f, 1.32f, 1.22f, 1.22f, 1.20f, 1.19f, 1.20f, 1.20f,
    1.16f, 2.20f, 1.95f, 1.90f, 1.75f, 1.64f, 1.54f, 1.47f, 1.46f, 1.42f, 1.39f, 1.45f,
    1.44f, 1.42f, 1.39f, 1.39f, 1.38f, 1.39f, 1.40f, 2.44f, 2.15f, 2.07f, 2.04f, 2.03f,
    2.01f, 1.99f, 1.98f, 1.98f, 1.96f, 1.94f, 1.92f, 1.92f, 1.89f, 1.90f, 1.87f, 1.87f,
    1.75f, 1.70f, 1.62f, 1.51f, 1.44f, 1.41f, 1.36f, 1.36f, 1.32f, 1.45f, 1.46f, 1.48f,
    1.40f, 1.50f, 1.50f, 2.60f, 2.21f, 2.15f, 2.06f, 2.00f, 1.96f, 1.90f, 1.87f, 1.80f,
    1.69f,
    0.2f, 0.2f, 0.2f, 0.2f, 0.2f, 0.2f, 0.2f, 0.2f, 0.2f, 0.2f, 0.2f,
    0.2f, 0.2f, 0.2f, 0.2f, 0.2f, 0.2f, 0.2f, 0.2f, 0.2f, 0.2f, 0.2f
};

// ---------------- per-node elem id: bytes (fallback) + 4-bit packed (fused);
// block 0 builds the element table and initializes the work-steal ticket.
__global__ __launch_bounds__(256)
void zbl_node_elem(const float* __restrict__ node_attrs,
                   const int* __restrict__ atomic_numbers,
                   unsigned char* __restrict__ elem,
                   unsigned char* __restrict__ packed,
                   float4* __restrict__ etab_g,
                   int* __restrict__ ctr, int ctr_init, int n_nodes) {
    __shared__ float rows[256 * 11];          // stride 11: bank-conflict-free
    __shared__ unsigned char earr[256];
    int t = threadIdx.x;
    if (blockIdx.x == 0) {
        if (t < NELEMS) {
            int Z = atomic_numbers[t];
            float zf = (float)Z;
            etab_g[t] = make_float4(zf, powf(zf, 0.3f), c_cov[Z], 0.0f);
        }
        if (t == 0) ctr[0] = ctr_init;
    }
    int n0 = blockIdx.x * 256;
    int nrow = min(256, n_nodes - n0);
    int nflt = nrow * NELEMS;
    const float* src = node_attrs + (size_t)n0 * NELEMS;
    for (int i = t; i < nflt; i += 256) {
        int rr = i / NELEMS, cc = i - rr * NELEMS;
        rows[rr * 11 + cc] = src[i];
    }
    __syncthreads();
    if (t < nrow) {
        const float* a = rows + t * 11;
        int best = 0;
        float bv = a[0];
#pragma unroll
        for (int k = 1; k < NELEMS; ++k) {
            float v = a[k];
            if (v > bv) { bv = v; best = k; }
        }
        earr[t] = (unsigned char)best;
        elem[n0 + t] = (unsigned char)best;
    }
    __syncthreads();
    if (t < 128 && 2 * t < nrow) {
        unsigned char lo = earr[2 * t];
        unsigned char hi = (2 * t + 1 < nrow) ? earr[2 * t + 1] : 0;
        packed[(n0 >> 1) + t] = (unsigned char)(lo | (hi << 4));
    }
}

__device__ __forceinline__ float zbl_edge_value_p(float xv, float A, float B,
                                                  float C) {
    float roa = xv * B;
    float phi = 0.1818f  * __expf(-3.2f    * roa)
              + 0.5099f  * __expf(-0.9423f * roa)
              + 0.2802f  * __expf(-0.4028f * roa)
              + 0.02817f * __expf(-0.2016f * roa);
    float v = A / xv * phi;
    float rr = xv / C;
    float rr2 = rr * rr;
    float rr3 = rr2 * rr;
    float rr6 = rr3 * rr3;
    float rr7 = rr6 * rr;
    float rr8 = rr7 * rr;
    float env = 1.0f - 28.0f * rr6 + 48.0f * rr7 - 21.0f * rr8;
    env = (xv < C) ? env : 0.0f;
    return 0.5f * v * env;
}

#define LOADBURST(c, RV, SV, XV)                                          \
    do {                                                                  \
        int _e0 = (c) * CHUNK;                                            \
        const int4*   _rp = (const int4*)(recv + _e0);                    \
        const int4*   _sp = (const int4*)(send + _e0);                    \
        const float4* _xp = (const float4*)(x + _e0);                     \
        int4 _ra = _rp[2 * t], _rb = _rp[2 * t + 1];                      \
        int4 _sa = _sp[2 * t], _sb = _sp[2 * t + 1];                      \
        float4 _xa = _xp[2 * t], _xb = _xp[2 * t + 1];                    \
        RV[0]=_ra.x; RV[1]=_ra.y; RV[2]=_ra.z; RV[3]=_ra.w;               \
        RV[4]=_rb.x; RV[5]=_rb.y; RV[6]=_rb.z; RV[7]=_rb.w;               \
        SV[0]=_sa.x; SV[1]=_sa.y; SV[2]=_sa.z; SV[3]=_sa.w;               \
        SV[4]=_sb.x; SV[5]=_sb.y; SV[6]=_sb.z; SV[7]=_sb.w;               \
        XV[0]=_xa.x; XV[1]=_xa.y; XV[2]=_xa.z; XV[3]=_xa.w;               \
        XV[4]=_xb.x; XV[5]=_xb.y; XV[6]=_xb.z; XV[7]=_xb.w;               \
    } while (0)

#define SCAN_W0()                                                         \
    do {                                                                  \
        if (t < 64) {                                                     \
            int a = (t < nb)      ? ((cntA[t]      + (PAD-1)) & ~(PAD-1)) : 0; \
            int b = (t + 64 < nb) ? ((cntA[t + 64] + (PAD-1)) & ~(PAD-1)) : 0; \
            int a0 = a, b0 = b;                                           \
            _Pragma("unroll")                                             \
            for (int d = 1; d < 64; d <<= 1) {                            \
                int va = __shfl_up(a, d);                                 \
                int vb = __shfl_up(b, d);                                 \
                if (t >= d) { a += va; b += vb; }                         \
            }                                                             \
            int totA = __shfl(a, 63);                                     \
            b += totA;                                                    \
            lds_off[t + 1]  = a;                                          \
            lds_off[t + 65] = b;                                          \
            curB[t]       = a - a0;                                       \
            curB[t + 64]  = b - b0;                                       \
            cntA[t] = 0; cntA[t + 64] = 0;                                \
            if (t == 0) lds_off[0] = 0;                                   \
        }                                                                 \
    } while (0)

// ---------------- Fused persistent + work-stealing: per-edge ZBL value +
// counting sort into fixed per-chunk slabs. pk map LDS-resident (once/block);
// 3 barriers/chunk; next chunk stolen one iteration ahead so its prefetch
// burst issues a full place-phase before the counts need it.
__global__ __launch_bounds__(BS)
void zbl_fused(const float* __restrict__ x,
               const int* __restrict__ ei,
               const unsigned char* __restrict__ packed,
               const float4* __restrict__ etab_g,
               int* __restrict__ ctr,
               int n_edges, int n_nodes, int nb, int slab, int nchunks,
               float* __restrict__ valg,
               unsigned short* __restrict__ lrg,
               int* __restrict__ offg /*[c*(nb+1)+b]*/) {
    __shared__ unsigned char  pk[PKCAP];
    __shared__ float          val_s[SLABCAP];
    __shared__ unsigned short lr_s[SLABCAP];
    __shared__ int   lds_off[MAXBL + 1];
    __shared__ int   curB[MAXBL];
    __shared__ int   cntA[MAXBL];
    __shared__ int   sh_nx[2];
    __shared__ float ptabA[NELEMS * NELEMS];
    __shared__ float ptabB[NELEMS * NELEMS];
    __shared__ float ptabC[NELEMS * NELEMS];

    int t = threadIdx.x;
    const int* send = ei;
    const int* recv = ei + n_edges;

    int c = blockIdx.x;
    if (c >= nchunks) return;

    // ---- one-time init: pk copy + ptab + staging zero + cntA zero + steal#0
    if (t == 0) sh_nx[0] = atomicAdd(ctr, 1);   // next chunk (device ticket)
    {
        const unsigned int* ps = (const unsigned int*)packed;
        unsigned int* pd = (unsigned int*)pk;
        int npk = (n_nodes + 1) >> 1;
        int nw = npk >> 2;
        for (int i = t; i < nw; i += BS) pd[i] = ps[i];
        for (int i = (nw << 2) + t; i < npk; i += BS) pk[i] = packed[i];
    }
    for (int i = t; i < (SLABCAP >> 2); i += BS) {
        ((float4*)val_s)[i] = make_float4(0.f, 0.f, 0.f, 0.f);
        ((uint2*)lr_s)[i]   = make_uint2(0u, 0u);
    }
    if (t < MAXBL) cntA[t] = 0;
    if (t < NELEMS * NELEMS) {
        float4 u = etab_g[t / NELEMS];
        float4 v = etab_g[t % NELEMS];
        ptabA[t] = 14.3996f * u.x * v.x;
        ptabB[t] = (u.y + v.y) * INV_A_PREF;
        ptabC[t] = u.z + v.z;
    }

    // ---- prologue: load + count + scan for first chunk
    int rv[EPT], sv[EPT];
    float xv[EPT];
    bool full = (c * CHUNK + CHUNK <= n_edges);
    if (full) LOADBURST(c, rv, sv, xv);
    __syncthreads();   // init done; sh_nx[0] visible

    if (full) {
#pragma unroll
        for (int i = 0; i < EPT; ++i) atomicAdd(&cntA[rv[i] >> W_SHIFT], 1);
    } else {
        for (int e = c * CHUNK + t; e < n_edges; e += BS)
            atomicAdd(&cntA[recv[e] >> W_SHIFT], 1);
    }
    __syncthreads();   // counts ready
    SCAN_W0();
    __syncthreads();   // offsets + cursors ready

    int parity = 0;

    // ---- steady loop: 3 barriers per chunk
    while (true) {
        int n = sh_nx[parity];
        bool has_next = (n < nchunks);
        bool nfull = has_next && (n * CHUNK + CHUNK <= n_edges);
        int rv2[EPT], sv2[EPT];
        float xv2[EPT];
        if (nfull) LOADBURST(n, rv2, sv2, xv2);   // prefetch: in flight below
        if (t == 0 && has_next)
            sh_nx[parity ^ 1] = atomicAdd(ctr, 1); // steal for NEXT iteration

        // place current chunk (exp math + LDS scatter)
        if (full) {
#pragma unroll
            for (int i = 0; i < EPT; ++i) {
                int s = sv[i], r = rv[i];
                int es = (pk[s >> 1] >> ((s & 1) << 2)) & 15;
                int er = (pk[r >> 1] >> ((r & 1) << 2)) & 15;
                int pi = es * NELEMS + er;
                float v = zbl_edge_value_p(xv[i], ptabA[pi], ptabB[pi], ptabC[pi]);
                int pos = atomicAdd(&curB[r >> W_SHIFT], 1);
                val_s[pos] = v;
                lr_s[pos] = (unsigned short)(r & (W - 1));
            }
        } else {
            for (int e = c * CHUNK + t; e < n_edges; e += BS) {
                int s = send[e], r = recv[e];
                int es = (pk[s >> 1] >> ((s & 1) << 2)) & 15;
                int er = (pk[r >> 1] >> ((r & 1) << 2)) & 15;
                int pi = es * NELEMS + er;
                float v = zbl_edge_value_p(x[e], ptabA[pi], ptabB[pi], ptabC[pi]);
                int pos = atomicAdd(&curB[r >> W_SHIFT], 1);
                val_s[pos] = v;
                lr_s[pos] = (unsigned short)(r & (W - 1));
            }
        }
        __syncthreads();   // B1: staging complete (sh_nx[parity^1] also visible)

        // writeout current  ||  count next
        {
            int total = lds_off[nb];       // multiple of PAD
            size_t gb = (size_t)c * slab;
            float4* vdst = (float4*)(valg + gb);
            uint2*  ldst = (uint2*)(lrg + gb);
            int nt4 = total >> 2;
            for (int i = t; i < nt4; i += BS) {
                vdst[i] = ((float4*)val_s)[i];
                ldst[i] = ((uint2*)lr_s)[i];
            }
            if (t <= nb) offg[c * (nb + 1) + t] = lds_off[t];
        }
        if (has_next) {
            if (nfull) {
#pragma unroll
                for (int i = 0; i < EPT; ++i)
                    atomicAdd(&cntA[rv2[i] >> W_SHIFT], 1);
            } else {
                for (int e = n * CHUNK + t; e < n_edges; e += BS)
                    atomicAdd(&cntA[recv[e] >> W_SHIFT], 1);
            }
        }
        __syncthreads();   // B2: writeout done, next counts ready

        if (!has_next) break;

        // zero staging (waves 1-7)  ||  scan next (wave 0)
        if (t >= 64) {
            for (int i = t - 64; i < (SLABCAP >> 2); i += BS - 64) {
                ((float4*)val_s)[i] = make_float4(0.f, 0.f, 0.f, 0.f);
                ((uint2*)lr_s)[i]   = make_uint2(0u, 0u);
            }
        } else {
            SCAN_W0();
        }
        __syncthreads();   // B3: staging zeroed, offsets + cursors ready

        c = n;
        full = nfull;
        parity ^= 1;
#pragma unroll
        for (int i = 0; i < EPT; ++i) {
            rv[i] = rv2[i]; sv[i] = sv2[i]; xv[i] = xv2[i];
        }
    }
}

// ---------------- Pass 3: per-(bucket, slab-slice) segment reduction.
// 16-lane sub-waves each own a slab; float4/ushort4 loads (4 entries/lane).
__global__ __launch_bounds__(BS)
void zbl_reduce_seg(const float* __restrict__ valg,
                    const unsigned short* __restrict__ lrg,
                    const int* __restrict__ offg,
                    int nblk, int nb, int kred, int slab,
                    float* __restrict__ partial) {
    __shared__ float acc[W];
    int b = blockIdx.x;
    int j = blockIdx.y;
    int t = threadIdx.x;
    acc[t] = 0.0f;
    acc[t + BS] = 0.0f;
    __syncthreads();

    int stride = (nblk + kred - 1) / kred;
    int blk0 = j * stride;
    int blk1 = min(nblk, blk0 + stride);
    int wave = t >> 6, lane = t & 63;
    int sw = lane >> 4, li = lane & 15;           // 4 sub-waves of 16 lanes
    const int NSW = (BS / 64) * 4;                // 32 concurrent sub-waves

    for (int blk = blk0 + wave * 4 + sw; blk < blk1; blk += NSW) {
        const int* po = offg + (size_t)blk * (nb + 1) + b;
        int s0 = po[0], s1 = po[1];               // multiples of 4
        size_t gb = (size_t)blk * slab;
        const float4*  v4 = (const float4*)(valg + gb);
        const ushort4* l4 = (const ushort4*)(lrg + gb);
        for (int q = (s0 >> 2) + li; q < (s1 >> 2); q += 16) {
            float4  v = v4[q];
            ushort4 l = l4[q];
            atomicAdd(&acc[l.x], v.x);
            atomicAdd(&acc[l.y], v.y);
            atomicAdd(&acc[l.z], v.z);
            atomicAdd(&acc[l.w], v.w);
        }
    }
    __syncthreads();
    float* dst = partial + (((size_t)b * kred + j) << W_SHIFT);
    dst[t] = acc[t];
    dst[t + BS] = acc[t + BS];
}

// ---------------- Pass 4: sum kred partials per node -> out (float4)
__global__ void zbl_combine(const float* __restrict__ partial, int kred,
                            int n_nodes, float* __restrict__ out) {
    int q = blockIdx.x * blockDim.x + threadIdx.x;   // float4 index
    int n = q << 2;
    if (n >= n_nodes) return;
    int b = n >> W_SHIFT;
    int t = n & (W - 1);
    float4 s = make_float4(0.f, 0.f, 0.f, 0.f);
    for (int j = 0; j < kred; ++j) {
        const float4* p =
            (const float4*)(partial + (((size_t)b * kred + j) << W_SHIFT) + t);
        float4 v = *p;
        s.x += v.x; s.y += v.y; s.z += v.z; s.w += v.w;
    }
    if (n + 3 < n_nodes) {
        *(float4*)(out + n) = s;
    } else {
        out[n] = s.x;
        if (n + 1 < n_nodes) out[n + 1] = s.y;
        if (n + 2 < n_nodes) out[n + 2] = s.z;
    }
}

// ---------------- Fallback: direct global-atomic path
__global__ void zbl_edge_atomic(const float* __restrict__ x,
                                const int* __restrict__ edge_index,
                                const unsigned char* __restrict__ elem,
                                const float4* __restrict__ etab_g,
                                float* __restrict__ out, int n_edges) {
    int e = blockIdx.x * blockDim.x + threadIdx.x;
    if (e >= n_edges) return;
    int s = edge_index[e];
    int r = edge_index[n_edges + e];
    float4 u = etab_g[elem[s]];
    float4 w = etab_g[elem[r]];
    float v = zbl_edge_value_p(x[e], 14.3996f * u.x * w.x,
                               (u.y + w.y) * INV_A_PREF, u.z + w.z);
#if defined(__HIP_PLATFORM_AMD__)
    unsafeAtomicAdd(out + r, v);
#else
    atomicAdd(out + r, v);
#endif
}

extern "C" void kernel_launch(void* const* d_in, const int* in_sizes, int n_in,
                              void* d_out, int out_size, void* d_ws, size_t ws_size,
                              hipStream_t stream) {
    const float* x              = (const float*)d_in[0];
    const float* node_attrs     = (const float*)d_in[1];
    const int*   edge_index     = (const int*)d_in[2];
    const int*   atomic_numbers = (const int*)d_in[3];
    float*       out            = (float*)d_out;

    int n_edges = in_sizes[0];            // x is [E,1]
    int n_nodes = in_sizes[1] / NELEMS;   // node_attrs is [N,10]
    int nb = (n_nodes + W - 1) / W;       // buckets of 1024 nodes
    int nblk = (n_edges + CHUNK - 1) / CHUNK;
    int slab = (CHUNK + nb * (PAD - 1) + 3) & ~3;

    char* ws = (char*)d_ws;

    // workspace layout; pick largest kred that fits
    int kred = 0;
    size_t elem_o = 0, pk_o = 0, etab_o = 0, ctr_o = 0,
           val_o = 0, lr_o = 0, offg_o = 0, part_o = 0;
    for (int try_k = 8; try_k >= 1; try_k >>= 1) {
        size_t off = 0;
        auto alloc = [&](size_t bytes) {
            size_t o = off;
            off = (off + bytes + 255) & ~(size_t)255;
            return o;
        };
        elem_o = alloc((size_t)n_nodes);
        pk_o   = alloc((size_t)(n_nodes + 1) / 2);
        etab_o = alloc(NELEMS * sizeof(float4));
        ctr_o  = alloc(4 * sizeof(int));
        val_o  = alloc((size_t)nblk * slab * sizeof(float));
        lr_o   = alloc((size_t)nblk * slab * sizeof(unsigned short));
        offg_o = alloc((size_t)nblk * (nb + 1) * sizeof(int));
        part_o = alloc((size_t)nb * try_k * W * sizeof(float));
        if (off <= ws_size) { kred = try_k; break; }
    }

    unsigned char* elem   = (unsigned char*)(ws + elem_o);
    unsigned char* packed = (unsigned char*)(ws + pk_o);
    float4* etab_g        = (float4*)(ws + etab_o);
    int* ctr              = (int*)(ws + ctr_o);

    int gridP = nblk < GRIDP ? nblk : GRIDP;

    int nb_nodes = (n_nodes + 255) / 256;
    zbl_node_elem<<<nb_nodes, 256, 0, stream>>>(node_attrs, atomic_numbers,
                                                elem, packed, etab_g,
                                                ctr, gridP, n_nodes);

    bool fast_ok = (kred >= 1) && (nb <= MAXBL) && (slab <= SLABCAP) &&
                   (((n_nodes + 1) >> 1) <= PKCAP);

    if (fast_ok) {
        float* valg         = (float*)(ws + val_o);
        unsigned short* lrg = (unsigned short*)(ws + lr_o);
        int* offg           = (int*)(ws + offg_o);
        float* partial      = (float*)(ws + part_o);

        zbl_fused<<<gridP, BS, 0, stream>>>(x, edge_index, packed, etab_g, ctr,
                                            n_edges, n_nodes, nb, slab, nblk,
                                            valg, lrg, offg);
        zbl_reduce_seg<<<dim3(nb, kred), BS, 0, stream>>>(valg, lrg, offg, nblk,
                                                          nb, kred, slab, partial);
        int nq = (n_nodes + 3) >> 2;
        zbl_combine<<<(nq + 255) / 256, 256, 0, stream>>>(partial, kred,
                                                          n_nodes, out);
    } else {
        // fallback: direct global-atomic path
        hipMemsetAsync(d_out, 0, (size_t)out_size * sizeof(float), stream);
        int nb_edges = (n_edges + 255) / 256;
        zbl_edge_atomic<<<nb_edges, 255 + 1, 0, stream>>>(x, edge_index, elem,
                                                          etab_g, out, n_edges);
    }
}

// Round 13
// 56.957 us; speedup vs baseline: 1.0927x; 1.0927x over previous
//
#include <hip/hip_runtime.h>

#define NELEMS 10
#define W_SHIFT 10             // bucket width = 1024 nodes
#define W 1024
#define MAXBL 128              // max buckets supported by LDS arrays
#define CHUNK 4096             // edges per sort chunk
#define EPT 8                  // edges per thread (CHUNK / BS)
#define BS 512
#define PAD 4                  // segment padding (uint4 alignment)
#define SLABCAP (CHUNK + MAXBL * (PAD - 1))   // 4480
#define PKCAP 50176            // 49KB packed elem capacity (<=100352 nodes)
#define GRIDP 512              // persistent blocks (2 per CU)
#define INV_A_PREF (1.0f / (0.4543f * 0.529f))

// ase covalent radii (Cordero 2008), padded to 119
__constant__ float c_cov[119] = {
    0.2f, 0.31f, 0.28f, 1.28f, 0.96f, 0.84f, 0.76f, 0.71f, 0.66f, 0.57f, 0.58f, 1.66f,
    1.41f, 1.21f, 1.11f, 1.07f, 1.05f, 1.02f, 1.06f, 2.03f, 1.76f, 1.70f, 1.60f, 1.53f,
    1.39f, 1.39f, 1.32f, 1.26f, 1.24f, 1.32f, 1.22f, 1.22f, 1.20f, 1.19f, 1.20f, 1.20f,
    1.16f, 2.20f, 1.95f, 1.90f, 1.75f, 1.64f, 1.54f, 1.47f, 1.46f, 1.42f, 1.39f, 1.45f,
    1.44f, 1.42f, 1.39f, 1.39f, 1.38f, 1.39f, 1.40f, 2.44f, 2.15f, 2.07f, 2.04f, 2.03f,
    2.01f, 1.99f, 1.98f, 1.98f, 1.96f, 1.94f, 1.92f, 1.92f, 1.89f, 1.90f, 1.87f, 1.87f,
    1.75f, 1.70f, 1.62f, 1.51f, 1.44f, 1.41f, 1.36f, 1.36f, 1.32f, 1.45f, 1.46f, 1.48f,
    1.40f, 1.50f, 1.50f, 2.60f, 2.21f, 2.15f, 2.06f, 2.00f, 1.96f, 1.90f, 1.87f, 1.80f,
    1.69f,
    0.2f, 0.2f, 0.2f, 0.2f, 0.2f, 0.2f, 0.2f, 0.2f, 0.2f, 0.2f, 0.2f,
    0.2f, 0.2f, 0.2f, 0.2f, 0.2f, 0.2f, 0.2f, 0.2f, 0.2f, 0.2f, 0.2f
};

// pack: low 16 = bf16(val) (round-to-nearest), high 16 = local node id
__device__ __forceinline__ unsigned int pack_vl(float v, int lr) {
    unsigned int b = __float_as_uint(v);
    b += 0x8000u;
    return (b >> 16) | ((unsigned int)lr << 16);
}
__device__ __forceinline__ float unpack_v(unsigned int p) {
    return __uint_as_float(p << 16);
}

// ---------------- per-node elem id: bytes (fallback) + 4-bit packed (fused);
// block 0 also builds the 10-entry (Z, Z^0.3, cov) element table.
__global__ __launch_bounds__(256)
void zbl_node_elem(const float* __restrict__ node_attrs,
                   const int* __restrict__ atomic_numbers,
                   unsigned char* __restrict__ elem,
                   unsigned char* __restrict__ packed,
                   float4* __restrict__ etab_g, int n_nodes) {
    __shared__ float rows[256 * 11];          // stride 11: bank-conflict-free
    __shared__ unsigned char earr[256];
    int t = threadIdx.x;
    if (blockIdx.x == 0 && t < NELEMS) {
        int Z = atomic_numbers[t];
        float zf = (float)Z;
        etab_g[t] = make_float4(zf, powf(zf, 0.3f), c_cov[Z], 0.0f);
    }
    int n0 = blockIdx.x * 256;
    int nrow = min(256, n_nodes - n0);
    int nflt = nrow * NELEMS;
    const float* src = node_attrs + (size_t)n0 * NELEMS;
    for (int i = t; i < nflt; i += 256) {
        int rr = i / NELEMS, cc = i - rr * NELEMS;
        rows[rr * 11 + cc] = src[i];
    }
    __syncthreads();
    if (t < nrow) {
        const float* a = rows + t * 11;
        int best = 0;
        float bv = a[0];
#pragma unroll
        for (int k = 1; k < NELEMS; ++k) {
            float v = a[k];
            if (v > bv) { bv = v; best = k; }
        }
        earr[t] = (unsigned char)best;
        elem[n0 + t] = (unsigned char)best;
    }
    __syncthreads();
    if (t < 128 && 2 * t < nrow) {
        unsigned char lo = earr[2 * t];
        unsigned char hi = (2 * t + 1 < nrow) ? earr[2 * t + 1] : 0;
        packed[(n0 >> 1) + t] = (unsigned char)(lo | (hi << 4));
    }
}

__device__ __forceinline__ float zbl_edge_value_p(float xv, float A, float B,
                                                  float C) {
    float roa = xv * B;
    float phi = 0.1818f  * __expf(-3.2f    * roa)
              + 0.5099f  * __expf(-0.9423f * roa)
              + 0.2802f  * __expf(-0.4028f * roa)
              + 0.02817f * __expf(-0.2016f * roa);
    float v = A / xv * phi;
    float rr = xv / C;
    float rr2 = rr * rr;
    float rr3 = rr2 * rr;
    float rr6 = rr3 * rr3;
    float rr7 = rr6 * rr;
    float rr8 = rr7 * rr;
    float env = 1.0f - 28.0f * rr6 + 48.0f * rr7 - 21.0f * rr8;
    env = (xv < C) ? env : 0.0f;
    return 0.5f * v * env;
}

#define LOADBURST(c, RV, SV, XV)                                          \
    do {                                                                  \
        int _e0 = (c) * CHUNK;                                            \
        const int4*   _rp = (const int4*)(recv + _e0);                    \
        const int4*   _sp = (const int4*)(send + _e0);                    \
        const float4* _xp = (const float4*)(x + _e0);                     \
        int4 _ra = _rp[2 * t], _rb = _rp[2 * t + 1];                      \
        int4 _sa = _sp[2 * t], _sb = _sp[2 * t + 1];                      \
        float4 _xa = _xp[2 * t], _xb = _xp[2 * t + 1];                    \
        RV[0]=_ra.x; RV[1]=_ra.y; RV[2]=_ra.z; RV[3]=_ra.w;               \
        RV[4]=_rb.x; RV[5]=_rb.y; RV[6]=_rb.z; RV[7]=_rb.w;               \
        SV[0]=_sa.x; SV[1]=_sa.y; SV[2]=_sa.z; SV[3]=_sa.w;               \
        SV[4]=_sb.x; SV[5]=_sb.y; SV[6]=_sb.z; SV[7]=_sb.w;               \
        XV[0]=_xa.x; XV[1]=_xa.y; XV[2]=_xa.z; XV[3]=_xa.w;               \
        XV[4]=_xb.x; XV[5]=_xb.y; XV[6]=_xb.z; XV[7]=_xb.w;               \
    } while (0)

#define SCAN_W0()                                                         \
    do {                                                                  \
        if (t < 64) {                                                     \
            int a = (t < nb)      ? ((cntA[t]      + (PAD-1)) & ~(PAD-1)) : 0; \
            int b = (t + 64 < nb) ? ((cntA[t + 64] + (PAD-1)) & ~(PAD-1)) : 0; \
            int a0 = a, b0 = b;                                           \
            _Pragma("unroll")                                             \
            for (int d = 1; d < 64; d <<= 1) {                            \
                int va = __shfl_up(a, d);                                 \
                int vb = __shfl_up(b, d);                                 \
                if (t >= d) { a += va; b += vb; }                         \
            }                                                             \
            int totA = __shfl(a, 63);                                     \
            b += totA;                                                    \
            lds_off[t + 1]  = a;                                          \
            lds_off[t + 65] = b;                                          \
            curB[t]       = a - a0;                                       \
            curB[t + 64]  = b - b0;                                       \
            cntA[t] = 0; cntA[t + 64] = 0;                                \
            if (t == 0) lds_off[0] = 0;                                   \
        }                                                                 \
    } while (0)

// ---------------- Fused persistent (static chunk mapping): per-edge ZBL value
// + counting sort into fixed per-chunk slabs of PACKED u32 (bf16 val | lr).
// pk map LDS-resident (once/block); 3 barriers/chunk; next chunk's edge burst
// prefetched before the place phase.
__global__ __launch_bounds__(BS)
void zbl_fused(const float* __restrict__ x,
               const int* __restrict__ ei,
               const unsigned char* __restrict__ packed,
               const float4* __restrict__ etab_g,
               int n_edges, int n_nodes, int nb, int slab, int nchunks,
               unsigned int* __restrict__ pg,
               int* __restrict__ offg /*[c*(nb+1)+b]*/) {
    __shared__ unsigned char pk[PKCAP];
    __shared__ unsigned int  pg_s[SLABCAP];
    __shared__ int   lds_off[MAXBL + 1];
    __shared__ int   curB[MAXBL];
    __shared__ int   cntA[MAXBL];
    __shared__ float ptabA[NELEMS * NELEMS];
    __shared__ float ptabB[NELEMS * NELEMS];
    __shared__ float ptabC[NELEMS * NELEMS];

    int t = threadIdx.x;
    const int* send = ei;
    const int* recv = ei + n_edges;

    int c = blockIdx.x;
    if (c >= nchunks) return;

    // ---- one-time init: pk copy + ptab + staging zero + cntA zero
    {
        const unsigned int* ps = (const unsigned int*)packed;
        unsigned int* pd = (unsigned int*)pk;
        int npk = (n_nodes + 1) >> 1;
        int nw = npk >> 2;
        for (int i = t; i < nw; i += BS) pd[i] = ps[i];
        for (int i = (nw << 2) + t; i < npk; i += BS) pk[i] = packed[i];
    }
    for (int i = t; i < (SLABCAP >> 2); i += BS)
        ((uint4*)pg_s)[i] = make_uint4(0u, 0u, 0u, 0u);
    if (t < MAXBL) cntA[t] = 0;
    if (t < NELEMS * NELEMS) {
        float4 u = etab_g[t / NELEMS];
        float4 v = etab_g[t % NELEMS];
        ptabA[t] = 14.3996f * u.x * v.x;
        ptabB[t] = (u.y + v.y) * INV_A_PREF;
        ptabC[t] = u.z + v.z;
    }

    // ---- prologue: load + count + scan for first chunk
    int rv[EPT], sv[EPT];
    float xv[EPT];
    bool full = (c * CHUNK + CHUNK <= n_edges);
    if (full) LOADBURST(c, rv, sv, xv);
    __syncthreads();   // init + loads in flight

    if (full) {
#pragma unroll
        for (int i = 0; i < EPT; ++i) atomicAdd(&cntA[rv[i] >> W_SHIFT], 1);
    } else {
        for (int e = c * CHUNK + t; e < n_edges; e += BS)
            atomicAdd(&cntA[recv[e] >> W_SHIFT], 1);
    }
    __syncthreads();   // counts ready
    SCAN_W0();
    __syncthreads();   // offsets + cursors ready

    // ---- steady loop: 3 barriers per chunk
    while (true) {
        int n = c + gridDim.x;
        bool has_next = (n < nchunks);
        bool nfull = has_next && (n * CHUNK + CHUNK <= n_edges);
        int rv2[EPT], sv2[EPT];
        float xv2[EPT];
        if (nfull) LOADBURST(n, rv2, sv2, xv2);   // prefetch: in flight below

        // place current chunk (exp math + LDS scatter of packed u32)
        if (full) {
#pragma unroll
            for (int i = 0; i < EPT; ++i) {
                int s = sv[i], r = rv[i];
                int es = (pk[s >> 1] >> ((s & 1) << 2)) & 15;
                int er = (pk[r >> 1] >> ((r & 1) << 2)) & 15;
                int pi = es * NELEMS + er;
                float v = zbl_edge_value_p(xv[i], ptabA[pi], ptabB[pi], ptabC[pi]);
                int pos = atomicAdd(&curB[r >> W_SHIFT], 1);
                pg_s[pos] = pack_vl(v, r & (W - 1));
            }
        } else {
            for (int e = c * CHUNK + t; e < n_edges; e += BS) {
                int s = send[e], r = recv[e];
                int es = (pk[s >> 1] >> ((s & 1) << 2)) & 15;
                int er = (pk[r >> 1] >> ((r & 1) << 2)) & 15;
                int pi = es * NELEMS + er;
                float v = zbl_edge_value_p(x[e], ptabA[pi], ptabB[pi], ptabC[pi]);
                int pos = atomicAdd(&curB[r >> W_SHIFT], 1);
                pg_s[pos] = pack_vl(v, r & (W - 1));
            }
        }
        __syncthreads();   // B1: staging complete

        // writeout current  ||  count next
        {
            int total = lds_off[nb];       // multiple of PAD
            uint4* pdst = (uint4*)(pg + (size_t)c * slab);
            int nt4 = total >> 2;
            for (int i = t; i < nt4; i += BS)
                pdst[i] = ((uint4*)pg_s)[i];
            if (t <= nb) offg[c * (nb + 1) + t] = lds_off[t];
        }
        if (has_next) {
            if (nfull) {
#pragma unroll
                for (int i = 0; i < EPT; ++i)
                    atomicAdd(&cntA[rv2[i] >> W_SHIFT], 1);
            } else {
                for (int e = n * CHUNK + t; e < n_edges; e += BS)
                    atomicAdd(&cntA[recv[e] >> W_SHIFT], 1);
            }
        }
        __syncthreads();   // B2: writeout done, next counts ready

        if (!has_next) break;

        // zero staging (waves 1-7)  ||  scan next (wave 0)
        if (t >= 64) {
            for (int i = t - 64; i < (SLABCAP >> 2); i += BS - 64)
                ((uint4*)pg_s)[i] = make_uint4(0u, 0u, 0u, 0u);
        } else {
            SCAN_W0();
        }
        __syncthreads();   // B3: staging zeroed, offsets + cursors ready

        c = n;
        full = nfull;
#pragma unroll
        for (int i = 0; i < EPT; ++i) {
            rv[i] = rv2[i]; sv[i] = sv2[i]; xv[i] = xv2[i];
        }
    }
}

// ---------------- Pass 3: per-(bucket, slab-slice) segment reduction.
// 16-lane sub-waves each own a slab; uint4 loads (4 packed entries/lane).
__global__ __launch_bounds__(BS)
void zbl_reduce_seg(const unsigned int* __restrict__ pg,
                    const int* __restrict__ offg,
                    int nblk, int nb, int kred, int slab,
                    float* __restrict__ partial) {
    __shared__ float acc[W];
    int b = blockIdx.x;
    int j = blockIdx.y;
    int t = threadIdx.x;
    acc[t] = 0.0f;
    acc[t + BS] = 0.0f;
    __syncthreads();

    int stride = (nblk + kred - 1) / kred;
    int blk0 = j * stride;
    int blk1 = min(nblk, blk0 + stride);
    int wave = t >> 6, lane = t & 63;
    int sw = lane >> 4, li = lane & 15;           // 4 sub-waves of 16 lanes
    const int NSW = (BS / 64) * 4;                // 32 concurrent sub-waves

    for (int blk = blk0 + wave * 4 + sw; blk < blk1; blk += NSW) {
        const int* po = offg + (size_t)blk * (nb + 1) + b;
        int s0 = po[0], s1 = po[1];               // multiples of 4
        const uint4* p4 = (const uint4*)(pg + (size_t)blk * slab);
        for (int q = (s0 >> 2) + li; q < (s1 >> 2); q += 16) {
            uint4 u = p4[q];
            atomicAdd(&acc[u.x >> 16], unpack_v(u.x));
            atomicAdd(&acc[u.y >> 16], unpack_v(u.y));
            atomicAdd(&acc[u.z >> 16], unpack_v(u.z));
            atomicAdd(&acc[u.w >> 16], unpack_v(u.w));
        }
    }
    __syncthreads();
    float* dst = partial + (((size_t)b * kred + j) << W_SHIFT);
    dst[t] = acc[t];
    dst[t + BS] = acc[t + BS];
}

// ---------------- Pass 4: sum kred partials per node -> out (float4)
__global__ void zbl_combine(const float* __restrict__ partial, int kred,
                            int n_nodes, float* __restrict__ out) {
    int q = blockIdx.x * blockDim.x + threadIdx.x;   // float4 index
    int n = q << 2;
    if (n >= n_nodes) return;
    int b = n >> W_SHIFT;
    int t = n & (W - 1);
    float4 s = make_float4(0.f, 0.f, 0.f, 0.f);
    for (int j = 0; j < kred; ++j) {
        const float4* p =
            (const float4*)(partial + (((size_t)b * kred + j) << W_SHIFT) + t);
        float4 v = *p;
        s.x += v.x; s.y += v.y; s.z += v.z; s.w += v.w;
    }
    if (n + 3 < n_nodes) {
        *(float4*)(out + n) = s;
    } else {
        out[n] = s.x;
        if (n + 1 < n_nodes) out[n + 1] = s.y;
        if (n + 2 < n_nodes) out[n + 2] = s.z;
    }
}

// ---------------- Fallback: direct global-atomic path
__global__ void zbl_edge_atomic(const float* __restrict__ x,
                                const int* __restrict__ edge_index,
                                const unsigned char* __restrict__ elem,
                                const float4* __restrict__ etab_g,
                                float* __restrict__ out, int n_edges) {
    int e = blockIdx.x * blockDim.x + threadIdx.x;
    if (e >= n_edges) return;
    int s = edge_index[e];
    int r = edge_index[n_edges + e];
    float4 u = etab_g[elem[s]];
    float4 w = etab_g[elem[r]];
    float v = zbl_edge_value_p(x[e], 14.3996f * u.x * w.x,
                               (u.y + w.y) * INV_A_PREF, u.z + w.z);
#if defined(__HIP_PLATFORM_AMD__)
    unsafeAtomicAdd(out + r, v);
#else
    atomicAdd(out + r, v);
#endif
}

extern "C" void kernel_launch(void* const* d_in, const int* in_sizes, int n_in,
                              void* d_out, int out_size, void* d_ws, size_t ws_size,
                              hipStream_t stream) {
    const float* x              = (const float*)d_in[0];
    const float* node_attrs     = (const float*)d_in[1];
    const int*   edge_index     = (const int*)d_in[2];
    const int*   atomic_numbers = (const int*)d_in[3];
    float*       out            = (float*)d_out;

    int n_edges = in_sizes[0];            // x is [E,1]
    int n_nodes = in_sizes[1] / NELEMS;   // node_attrs is [N,10]
    int nb = (n_nodes + W - 1) / W;       // buckets of 1024 nodes
    int nblk = (n_edges + CHUNK - 1) / CHUNK;
    int slab = (CHUNK + nb * (PAD - 1) + 3) & ~3;

    char* ws = (char*)d_ws;

    // workspace layout; pick largest kred that fits
    int kred = 0;
    size_t elem_o = 0, pk_o = 0, etab_o = 0,
           pg_o = 0, offg_o = 0, part_o = 0;
    for (int try_k = 8; try_k >= 1; try_k >>= 1) {
        size_t off = 0;
        auto alloc = [&](size_t bytes) {
            size_t o = off;
            off = (off + bytes + 255) & ~(size_t)255;
            return o;
        };
        elem_o = alloc((size_t)n_nodes);
        pk_o   = alloc((size_t)(n_nodes + 1) / 2);
        etab_o = alloc(NELEMS * sizeof(float4));
        pg_o   = alloc((size_t)nblk * slab * sizeof(unsigned int));
        offg_o = alloc((size_t)nblk * (nb + 1) * sizeof(int));
        part_o = alloc((size_t)nb * try_k * W * sizeof(float));
        if (off <= ws_size) { kred = try_k; break; }
    }

    unsigned char* elem   = (unsigned char*)(ws + elem_o);
    unsigned char* packed = (unsigned char*)(ws + pk_o);
    float4* etab_g        = (float4*)(ws + etab_o);

    int nb_nodes = (n_nodes + 255) / 256;
    zbl_node_elem<<<nb_nodes, 256, 0, stream>>>(node_attrs, atomic_numbers,
                                                elem, packed, etab_g, n_nodes);

    bool fast_ok = (kred >= 1) && (nb <= MAXBL) && (slab <= SLABCAP) &&
                   (((n_nodes + 1) >> 1) <= PKCAP);

    if (fast_ok) {
        unsigned int* pg = (unsigned int*)(ws + pg_o);
        int* offg        = (int*)(ws + offg_o);
        float* partial   = (float*)(ws + part_o);

        int gridP = nblk < GRIDP ? nblk : GRIDP;
        zbl_fused<<<gridP, BS, 0, stream>>>(x, edge_index, packed, etab_g,
                                            n_edges, n_nodes, nb, slab, nblk,
                                            pg, offg);
        zbl_reduce_seg<<<dim3(nb, kred), BS, 0, stream>>>(pg, offg, nblk,
                                                          nb, kred, slab, partial);
        int nq = (n_nodes + 3) >> 2;
        zbl_combine<<<(nq + 255) / 256, 256, 0, stream>>>(partial, kred,
                                                          n_nodes, out);
    } else {
        // fallback: direct global-atomic path
        hipMemsetAsync(d_out, 0, (size_t)out_size * sizeof(float), stream);
        int nb_edges = (n_edges + 255) / 256;
        zbl_edge_atomic<<<nb_edges, 256, 0, stream>>>(x, edge_index, elem, etab_g,
                                                      out, n_edges);
    }
}